// Round 32
// baseline (121.182 us; speedup 1.0000x reference)
//
#include <hip/hip_runtime.h>
#include <hip/hip_bf16.h>
#include <math.h>

// Problem constants (fixed by setup_inputs)
#define B_ 16
#define L_ 1024
#define E_ 512
#define H_ 8
#define DH 64

typedef unsigned short u16;
typedef __attribute__((ext_vector_type(8))) short bf16x8;
typedef __attribute__((ext_vector_type(8))) unsigned short u16x8;
typedef __attribute__((ext_vector_type(4))) float f32x4;
typedef __attribute__((ext_vector_type(16))) float f32x16;

#define MFMA16(A, B, C) __builtin_amdgcn_mfma_f32_16x16x32_bf16(A, B, C, 0, 0, 0)
#define MFMA32(A, B, C) __builtin_amdgcn_mfma_f32_32x32x16_bf16(A, B, C, 0, 0, 0)

__device__ inline u16 f2b(float x) {
    __hip_bfloat16 h = __float2bfloat16(x);
    u16 u; __builtin_memcpy(&u, &h, 2); return u;
}

// single-instruction 2^x
__device__ inline float exp2_hw(float x) {
    float r; asm("v_exp_f32 %0, %1" : "=v"(r) : "v"(x)); return r;
}

// hardware packed f32->bf16 (RNE), lo = a, hi = b
__device__ inline unsigned int cvt_pk_bf16(float a, float b) {
    unsigned int r;
    asm("v_cvt_pk_bf16_f32 %0, %1, %2" : "=v"(r) : "v"(a), "v"(b));
    return r;
}

// ---------------- fp32 -> bf16 conversion (w_in, w_out only) + qscale ------
__global__ __launch_bounds__(256) void cvt_bf16(
    const float* __restrict__ wi, const float* __restrict__ wo,
    const float* __restrict__ qs_scale,
    u16* __restrict__ wib, u16* __restrict__ wob, float* __restrict__ qscale)
{
    if (blockIdx.x == 0 && threadIdx.x < DH) {
        float s = qs_scale[threadIdx.x];
        float sp = (s > 20.f) ? s : log1pf(expf(s));
        qscale[threadIdx.x] = 1.442695041f * sp * 0.125f * 1.442695041f;
    }
    int i = blockIdx.x * 256 + threadIdx.x;   // 512 blocks -> 131072 chunks
    const float* src; u16* dst; size_t off;
    if (i < 98304) { src = wi; dst = wib; off = (size_t)i * 8; }
    else           { src = wo; dst = wob; off = (size_t)(i - 98304) * 8; }
    float4 a = *(const float4*)(src + off);
    float4 b = *(const float4*)(src + off + 4);
    u16x8 r;
    r[0] = f2b(a.x); r[1] = f2b(a.y); r[2] = f2b(a.z); r[3] = f2b(a.w);
    r[4] = f2b(b.x); r[5] = f2b(b.y); r[6] = f2b(b.z); r[7] = f2b(b.w);
    *(u16x8*)(dst + off) = r;
}

// ---------------- QKV GEMM: 256x128 tile, 8 waves, fp32-A in-register ------
// Round-32: BM=256 doubles MFMA work per barrier (32 MFMA16/wave/step) and
// halves block count; LDS 48KB -> 3 blocks/CU (24 waves/CU, up from 8).
// Staging maps identical in structure to the verified r28 gemm: fp32 A
// loaded as coalesced float4, cvt_pk to bf16, write-side XOR swizzle
// (thread covers slots tid, tid+512; swizzle invariant under row+128);
// B one-DMA-per-wave global_load_lds with inverse-XOR source.
__global__ __launch_bounds__(512) void gemm_qkv(
    const float* __restrict__ Af32, const u16* __restrict__ W,
    const float* __restrict__ bias, const float* __restrict__ qscale,
    u16* __restrict__ Qb, u16* __restrict__ Kb, u16* __restrict__ Vtb)
{
    __shared__ u16 sA[2][8192];                // 2 x 16KB (256x32 bf16)
    __shared__ u16 sB[2][4096];                // 2 x 8KB (128x32 bf16)
    const int tid = threadIdx.x;
    const int m0 = blockIdx.x * 256;
    const int n0 = blockIdx.y * 128;
    const int wid = tid >> 6, lane = tid & 63;
    const int g = lane >> 4, c = lane & 15;
    const int wr = wid >> 1, wc = wid & 1;     // wr 0..3 (64-row quads), wc 0..1

    // A fp32 staging: slots tid (rows 0..127) and tid+512 (rows 128..255)
    const int arow = tid >> 2;
    const int swgA = (arow & 3) ^ ((arow >> 2) & 3);   // same for arow+128
    const float* Afs = Af32 + (size_t)(m0 + arow) * 512 + (tid & 3) * 8;
    const int aslot0 = (arow * 4 + ((tid & 3) ^ swgA)) * 8;         // u16 idx
    const int aslot1 = ((arow + 128) * 4 + ((tid & 3) ^ swgA)) * 8;

    // B staging: slot tid (512 slots = 128 rows x 4 chunks); 1 DMA per wave
    const int brow = tid >> 2;
    const int bch = (tid & 3) ^ ((brow & 3) ^ ((brow >> 2) & 3));
    const u16* Bsrc = W + (size_t)(n0 + brow) * 512 + bch * 8;

    auto stageB = [&](int nbuf, int ks) {
        __builtin_amdgcn_global_load_lds(
            (const __attribute__((address_space(1))) unsigned int*)(Bsrc + ks * 32),
            (__attribute__((address_space(3))) unsigned int*)&sB[nbuf][wid * 512],
            16, 0, 0);
    };

    f32x4 acc[4][4];
    #pragma unroll
    for (int m = 0; m < 4; m++)
        #pragma unroll
        for (int n = 0; n < 4; n++) acc[m][n] = (f32x4){0.f, 0.f, 0.f, 0.f};

    const int swr = (c & 3) ^ ((c >> 2) & 3);
    const int chA = (g ^ swr) * 8;

    float4 a0, a1, a2, a3;
    a0 = *(const float4*)(Afs);
    a1 = *(const float4*)(Afs + 4);
    a2 = *(const float4*)(Afs + (size_t)128 * 512);
    a3 = *(const float4*)(Afs + (size_t)128 * 512 + 4);
    stageB(0, 0);

    #pragma unroll 1
    for (int ks = 0; ks < 16; ks++) {
        const int cur = ks & 1;
        // convert + write A(ks) into sA[cur] (auto vmcnt wait on a0..a3)
        uint4 w0, w1;
        w0.x = cvt_pk_bf16(a0.x, a0.y); w0.y = cvt_pk_bf16(a0.z, a0.w);
        w0.z = cvt_pk_bf16(a1.x, a1.y); w0.w = cvt_pk_bf16(a1.z, a1.w);
        w1.x = cvt_pk_bf16(a2.x, a2.y); w1.y = cvt_pk_bf16(a2.z, a2.w);
        w1.z = cvt_pk_bf16(a3.x, a3.y); w1.w = cvt_pk_bf16(a3.z, a3.w);
        *(uint4*)&sA[cur][aslot0] = w0;
        *(uint4*)&sA[cur][aslot1] = w1;
        asm volatile("s_waitcnt vmcnt(0) lgkmcnt(0)" ::: "memory");
        __builtin_amdgcn_s_barrier();
        asm volatile("" ::: "memory");
        if (ks < 15) {
            const float* p = Afs + (ks + 1) * 32;
            a0 = *(const float4*)(p);
            a1 = *(const float4*)(p + 4);
            a2 = *(const float4*)(p + (size_t)128 * 512);
            a3 = *(const float4*)(p + (size_t)128 * 512 + 4);
            stageB(cur ^ 1, ks + 1);           // after barrier: readers done
        }

        bf16x8 af[4], bfr[4];
        #pragma unroll
        for (int m = 0; m < 4; m++)
            af[m] = *(const bf16x8*)&sA[cur][(wr * 64 + m * 16 + c) * 32 + chA];
        #pragma unroll
        for (int n = 0; n < 4; n++)
            bfr[n] = *(const bf16x8*)&sB[cur][(wc * 64 + n * 16 + c) * 32 + chA];
        #pragma unroll
        for (int m = 0; m < 4; m++)
            #pragma unroll
            for (int n = 0; n < 4; n++)
                acc[m][n] = MFMA16(af[m], bfr[n], acc[m][n]);
    }

    #pragma unroll
    for (int m = 0; m < 4; m++) {
        int rbase = m0 + wr * 64 + m * 16 + 4 * g;
        #pragma unroll
        for (int n = 0; n < 4; n++) {
            int f = n0 + wc * 64 + n * 16 + c;
            f32x4 v = acc[m][n];
            float bv = bias[f];
            int part = f >> 9, w = f & 511, h = w >> 6, d = w & 63;
            int bb = rbase >> 10;
            int l0 = rbase & 1023;
            size_t bh = (size_t)(bb * H_ + h);
            if (part == 0) {
                float qs = qscale[d];
                #pragma unroll
                for (int reg = 0; reg < 4; reg++)
                    Qb[(bh * L_ + l0 + reg) * DH + d] = f2b((v[reg] + bv) * qs);
            } else if (part == 1) {
                #pragma unroll
                for (int reg = 0; reg < 4; reg++)
                    Kb[(bh * L_ + l0 + reg) * DH + d] = f2b(v[reg] + bv);
            } else {
                ushort4 pk;
                pk.x = f2b(v[0] + bv); pk.y = f2b(v[1] + bv);
                pk.z = f2b(v[2] + bv); pk.w = f2b(v[3] + bv);
                *(ushort4*)(Vtb + (bh * DH + d) * L_ + l0) = pk;
            }
        }
    }
}

// ---------------- out-proj GEMM (verified r28 structure, MODE 1 only) ------
__global__ __launch_bounds__(256) void gemm_out(
    const u16* __restrict__ A16, const u16* __restrict__ W,
    const float* __restrict__ bias, float* __restrict__ Dout)
{
    __shared__ u16 sA[2][4096];                // 2 x 8KB (512 slots x 16B)
    __shared__ u16 sB[2][4096];
    const int tid = threadIdx.x;
    const int m0 = blockIdx.x * 128;
    const int n0 = blockIdx.y * 128;
    const int wid = tid >> 6, lane = tid & 63;
    const int g = lane >> 4, c = lane & 15;
    const int wr = wid >> 1, wc = wid & 1;

    const int arow = tid >> 2;
    const int swg = (arow & 3) ^ ((arow >> 2) & 3);
    const int ch = (tid & 3) ^ swg;
    const u16* Bsrc = W + (size_t)(n0 + arow) * 512 + ch * 8;
    const u16* A16src = A16 + (size_t)(m0 + arow) * 512 + ch * 8;

    auto stageB = [&](int nbuf, int ks) {
        const int k0 = ks * 32;
        __builtin_amdgcn_global_load_lds(
            (const __attribute__((address_space(1))) unsigned int*)(Bsrc + k0),
            (__attribute__((address_space(3))) unsigned int*)&sB[nbuf][wid * 512], 16, 0, 0);
        __builtin_amdgcn_global_load_lds(
            (const __attribute__((address_space(1))) unsigned int*)(Bsrc + (size_t)64 * 512 + k0),
            (__attribute__((address_space(3))) unsigned int*)&sB[nbuf][2048 + wid * 512], 16, 0, 0);
    };
    auto stageA16 = [&](int nbuf, int ks) {
        const int k0 = ks * 32;
        __builtin_amdgcn_global_load_lds(
            (const __attribute__((address_space(1))) unsigned int*)(A16src + k0),
            (__attribute__((address_space(3))) unsigned int*)&sA[nbuf][wid * 512], 16, 0, 0);
        __builtin_amdgcn_global_load_lds(
            (const __attribute__((address_space(1))) unsigned int*)(A16src + (size_t)64 * 512 + k0),
            (__attribute__((address_space(3))) unsigned int*)&sA[nbuf][2048 + wid * 512], 16, 0, 0);
    };

    f32x4 acc[4][4];
    #pragma unroll
    for (int m = 0; m < 4; m++)
        #pragma unroll
        for (int n = 0; n < 4; n++) acc[m][n] = (f32x4){0.f, 0.f, 0.f, 0.f};

    const int swr = (c & 3) ^ ((c >> 2) & 3);
    const int chA = (g ^ swr) * 8;

    stageA16(0, 0);
    stageB(0, 0);

    #pragma unroll 1
    for (int ks = 0; ks < 16; ks++) {
        const int cur = ks & 1;
        asm volatile("s_waitcnt vmcnt(0) lgkmcnt(0)" ::: "memory");
        __builtin_amdgcn_s_barrier();
        asm volatile("" ::: "memory");
        if (ks < 15) {
            stageA16(cur ^ 1, ks + 1);
            stageB(cur ^ 1, ks + 1);
        }

        bf16x8 af[4], bfr[4];
        #pragma unroll
        for (int m = 0; m < 4; m++)
            af[m] = *(const bf16x8*)&sA[cur][(wr * 64 + m * 16 + c) * 32 + chA];
        #pragma unroll
        for (int n = 0; n < 4; n++)
            bfr[n] = *(const bf16x8*)&sB[cur][(wc * 64 + n * 16 + c) * 32 + chA];
        #pragma unroll
        for (int m = 0; m < 4; m++)
            #pragma unroll
            for (int n = 0; n < 4; n++)
                acc[m][n] = MFMA16(af[m], bfr[n], acc[m][n]);
    }

    #pragma unroll
    for (int m = 0; m < 4; m++) {
        int rbase = m0 + wr * 64 + m * 16 + 4 * g;
        #pragma unroll
        for (int n = 0; n < 4; n++) {
            int f = n0 + wc * 64 + n * 16 + c;
            f32x4 v = acc[m][n];
            float bv = bias[f];
            #pragma unroll
            for (int reg = 0; reg < 4; reg++)
                Dout[(size_t)(rbase + reg) * E_ + f] = v[reg] + bv;
        }
    }
}

// ---------------- MFMA flash attention, 8-wave blocks, role-split staging --
// (verified round-31: 512-thread blocks, 4 blocks/bh, wave-role-split K/V
// DMA, depth-3 counted vmcnt, no-shift softmax, denominator on MFMA, T12)
__global__ __launch_bounds__(512, 4) void attn_mfma(
    const u16* __restrict__ Q, const u16* __restrict__ K,
    const u16* __restrict__ Vt, const unsigned char* __restrict__ mask,
    u16* __restrict__ O)
{
    __shared__ u16 Kbuf[4][2048];              // 4 x 4KB (256 slots x 16B)
    __shared__ u16 Vbuf[4][2048];              // 4 x 4KB

    const int bid = blockIdx.x;                // 0..511
    const int w = (bid & 7) * 64 + (bid >> 3); // XCD-bijective swizzle
    const int bh = w >> 2;                     // 0..127
    const int blk = w & 3;                     // 0..3 within bh
    const int tid = threadIdx.x;
    const int wid = tid >> 6;                  // 0..7
    const int q0 = blk * 256 + wid * 32;       // wave's q base
    const int b = bh >> 3;
    const int h = bh & (H_ - 1);

    const int lane = tid & 63;
    const int c = lane & 31;                   // MFMA32 column
    const int hi = lane >> 5;

    const u16* Qp = Q + ((size_t)bh * L_ + q0) * DH;
    const u16* Kp = K + (size_t)bh * L_ * DH;
    const u16* Vp = Vt + (size_t)bh * DH * L_;
    const unsigned char* mp = mask + (size_t)b * L_;

    // role-split staging: wave quarter kvw covers slots [kvw*64, kvw*64+64)
    const int kvw = wid & 3;
    const bool isV = (wid >= 4);
    const int slot = kvw * 64 + lane;
    const int krow = slot >> 3, kch = (slot & 7) ^ (krow & 7);
    const int vrow = slot >> 2, vch = (slot & 3) ^ ((vrow & 3) ^ ((vrow >> 2) & 3));
    const u16* Kg = Kp + (size_t)krow * DH + kch * 8;   // + kt*DH per tile
    const u16* Vg = Vp + (size_t)vrow * L_ + vch * 8;   // + kt per tile

    auto stage = [&](int nbuf, int kt) {       // ONE DMA per wave
        if (!isV) {
            __builtin_amdgcn_global_load_lds(
                (const __attribute__((address_space(1))) unsigned int*)(Kg + (size_t)kt * DH),
                (__attribute__((address_space(3))) unsigned int*)&Kbuf[nbuf][kvw * 512],
                16, 0, 0);
        } else {
            __builtin_amdgcn_global_load_lds(
                (const __attribute__((address_space(1))) unsigned int*)(Vg + kt),
                (__attribute__((address_space(3))) unsigned int*)&Vbuf[nbuf][kvw * 512],
                16, 0, 0);
        }
    };

    // mask presence + Q fragments issued BEFORE the stages
    unsigned int mor = 0;
    {
        const unsigned int* mp32 = (const unsigned int*)mp;
        #pragma unroll
        for (int i = 0; i < 4; i++) mor |= mp32[lane + i * 64];
    }
    const bool anyMask = (__ballot(mor != 0) != 0ULL);

    bf16x8 qf[4];
    #pragma unroll
    for (int s2 = 0; s2 < 4; s2++)
        qf[s2] = *(const bf16x8*)(Qp + c * DH + s2 * 16 + hi * 8);

    stage(0, 0);                               // prefetch tiles 0,1,2
    stage(1, 32);
    stage(2, 64);

    f32x16 oacc0 = {}, oacc1 = {};
    f32x16 lacc = {};                          // denominator, row space

    // all-ones bf16 B-operand for the denominator matvec
    union { unsigned int u[4]; bf16x8 v; } onesu;
    onesu.u[0] = 0x3F803F80u; onesu.u[1] = 0x3F803F80u;
    onesu.u[2] = 0x3F803F80u; onesu.u[3] = 0x3F803F80u;
    const bf16x8 ones_b = onesu.v;

    // read-side swizzled LDS offsets (u16 indices)
    int kslot[4];
    #pragma unroll
    for (int s2 = 0; s2 < 4; s2++)
        kslot[s2] = (c * 8 + (((2 * s2 + hi)) ^ (c & 7))) * 8;
    const int swzv = (c & 3) ^ ((c >> 2) & 3);
    int vslot[2][2];
    #pragma unroll
    for (int dt = 0; dt < 2; dt++)
        #pragma unroll
        for (int s = 0; s < 2; s++)
            vslot[dt][s] = ((dt * 32 + c) * 4 + (((2 * s + hi)) ^ swzv)) * 8;

    #pragma unroll 1
    for (int t = 0; t < 32; ++t) {
        const int cur = t & 3;
        const int kt = t * 32;
        // counted wait: retire this wave's stage(t) (1 DMA per stage)
        if (t < 30)      { asm volatile("s_waitcnt vmcnt(2) lgkmcnt(0)" ::: "memory"); }
        else if (t == 30){ asm volatile("s_waitcnt vmcnt(1) lgkmcnt(0)" ::: "memory"); }
        else             { asm volatile("s_waitcnt vmcnt(0) lgkmcnt(0)" ::: "memory"); }
        __builtin_amdgcn_s_barrier();
        asm volatile("" ::: "memory");

        bf16x8 kf[4];
        #pragma unroll
        for (int s2 = 0; s2 < 4; s2++)
            kf[s2] = *(const bf16x8*)&Kbuf[cur][kslot[s2]];
        bf16x8 vf[2][2];
        #pragma unroll
        for (int dt = 0; dt < 2; dt++)
            #pragma unroll
            for (int s = 0; s < 2; s++)
                vf[dt][s] = *(const bf16x8*)&Vbuf[cur][vslot[dt][s]];

        if (t < 29) stage((t + 3) & 3, kt + 96);   // keep depth-3 in flight

        // S^T = K @ Q^T : lane holds S^T[key=(r&3)+8*(r>>2)+4*hi][q=c]
        f32x16 st = {};
        __builtin_amdgcn_s_setprio(1);
        #pragma unroll
        for (int s2 = 0; s2 < 4; s2++)
            st = MFMA32(kf[s2], qf[s2], st);
        __builtin_amdgcn_s_setprio(0);

        if (anyMask) {
            #pragma unroll
            for (int r = 0; r < 16; r++) {
                int key = kt + (r & 3) + 8 * (r >> 2) + 4 * hi;
                if (mp[key]) st[r] = -1e9f;
            }
        }

        // no-shift softmax: p = 2^st (shift unnecessary; ratio cancels it)
        float p[16];
        #pragma unroll
        for (int r = 0; r < 16; r++) p[r] = exp2_hw(st[r]);

        // in-register P redistribution (T12): cvt_pk + permlane32_swap
        unsigned int x0 = cvt_pk_bf16(p[0],  p[1]);
        unsigned int x1 = cvt_pk_bf16(p[2],  p[3]);
        unsigned int y0 = cvt_pk_bf16(p[4],  p[5]);
        unsigned int y1 = cvt_pk_bf16(p[6],  p[7]);
        unsigned int x2 = cvt_pk_bf16(p[8],  p[9]);
        unsigned int x3 = cvt_pk_bf16(p[10], p[11]);
        unsigned int y2 = cvt_pk_bf16(p[12], p[13]);
        unsigned int y3 = cvt_pk_bf16(p[14], p[15]);
        asm volatile("v_permlane32_swap_b32 %0, %1" : "+v"(x0), "+v"(y0));
        asm volatile("v_permlane32_swap_b32 %0, %1" : "+v"(x1), "+v"(y1));
        asm volatile("v_permlane32_swap_b32 %0, %1" : "+v"(x2), "+v"(y2));
        asm volatile("v_permlane32_swap_b32 %0, %1" : "+v"(x3), "+v"(y3));
        union { unsigned int u[4]; bf16x8 v; } pk0u, pk1u;
        pk0u.u[0] = x0; pk0u.u[1] = x1; pk0u.u[2] = y0; pk0u.u[3] = y1;
        pk1u.u[0] = x2; pk1u.u[1] = x3; pk1u.u[2] = y2; pk1u.u[3] = y3;
        bf16x8 pa0 = pk0u.v;                   // A[row=q=c][key=hi*8+j]
        bf16x8 pa1 = pk1u.v;                   // A[row=q=c][key=16+hi*8+j]

        __builtin_amdgcn_s_setprio(1);
        oacc0 = MFMA32(pa0, vf[0][0], oacc0);
        oacc0 = MFMA32(pa1, vf[0][1], oacc0);
        oacc1 = MFMA32(pa0, vf[1][0], oacc1);
        oacc1 = MFMA32(pa1, vf[1][1], oacc1);
        // denominator matvec: lacc[r] += sum_k P[q=(r&3)+8(r>>2)+4hi][k]
        lacc = MFMA32(pa0, ones_b, lacc);
        lacc = MFMA32(pa1, ones_b, lacc);
        __builtin_amdgcn_s_setprio(0);
        // oacc: lane holds O[q=(r&3)+8*(r>>2)+4*hi][d = dt*32 + c]
    }

    #pragma unroll
    for (int r = 0; r < 16; r++) {
        int row = (r & 3) + 8 * (r >> 2) + 4 * hi;
        float inv = 1.f / lacc[r];             // row space, no shfl needed
        size_t base = ((size_t)(b * L_ + q0 + row)) * E_ + h * DH + c;
        O[base] = f2b(oacc0[r] * inv);
        O[base + 32] = f2b(oacc1[r] * inv);
    }
}

// ---------------- host launch ----------------
extern "C" void kernel_launch(void* const* d_in, const int* in_sizes, int n_in,
                              void* d_out, int out_size, void* d_ws, size_t ws_size,
                              hipStream_t stream) {
    const float* x     = (const float*)d_in[0];
    const float* w_in  = (const float*)d_in[1];
    const float* b_in  = (const float*)d_in[2];
    const float* w_out = (const float*)d_in[3];
    const float* b_out = (const float*)d_in[4];
    const float* qs    = (const float*)d_in[5];
    const unsigned char* mask = (const unsigned char*)d_in[6];
    float* out = (float*)d_out;

    char* base = (char*)d_ws;
    const size_t NELEM = (size_t)B_ * L_ * E_;   // 8388608
    float* qscale = (float*)base;                // 256 B
    u16* wib = (u16*)(base + 256);               // 786432
    u16* wob = wib + 786432;                     // 262144
    u16* Qb  = wob + 262144;
    u16* Kb  = Qb + NELEM;
    u16* Vtb = Kb + NELEM;
    u16* Ob  = Vtb + NELEM;

    cvt_bf16<<<512, 256, 0, stream>>>(w_in, w_out, qs, wib, wob, qscale);
    gemm_qkv<<<dim3(64, 12), 512, 0, stream>>>(
        x, wib, b_in, qscale, Qb, Kb, Vtb);
    attn_mfma<<<dim3(512), 512, 0, stream>>>(Qb, Kb, Vtb, mask, Ob);
    gemm_out<<<dim3(128, 4), 256, 0, stream>>>(Ob, wob, b_out, out);
}

// Round 33
// 115.880 us; speedup vs baseline: 1.0458x; 1.0458x over previous
//
#include <hip/hip_runtime.h>
#include <hip/hip_bf16.h>
#include <math.h>

// Problem constants (fixed by setup_inputs)
#define B_ 16
#define L_ 1024
#define E_ 512
#define H_ 8
#define DH 64

typedef unsigned short u16;
typedef __attribute__((ext_vector_type(8))) short bf16x8;
typedef __attribute__((ext_vector_type(8))) unsigned short u16x8;
typedef __attribute__((ext_vector_type(4))) float f32x4;
typedef __attribute__((ext_vector_type(16))) float f32x16;

#define MFMA16(A, B, C) __builtin_amdgcn_mfma_f32_16x16x32_bf16(A, B, C, 0, 0, 0)
#define MFMA32(A, B, C) __builtin_amdgcn_mfma_f32_32x32x16_bf16(A, B, C, 0, 0, 0)

__device__ inline u16 f2b(float x) {
    __hip_bfloat16 h = __float2bfloat16(x);
    u16 u; __builtin_memcpy(&u, &h, 2); return u;
}

// single-instruction 2^x
__device__ inline float exp2_hw(float x) {
    float r; asm("v_exp_f32 %0, %1" : "=v"(r) : "v"(x)); return r;
}

// hardware packed f32->bf16 (RNE), lo = a, hi = b
__device__ inline unsigned int cvt_pk_bf16(float a, float b) {
    unsigned int r;
    asm("v_cvt_pk_bf16_f32 %0, %1, %2" : "=v"(r) : "v"(a), "v"(b));
    return r;
}

// ---------------- fp32 -> bf16 conversion (w_in, w_out only) + qscale ------
__global__ __launch_bounds__(256) void cvt_bf16(
    const float* __restrict__ wi, const float* __restrict__ wo,
    const float* __restrict__ qs_scale,
    u16* __restrict__ wib, u16* __restrict__ wob, float* __restrict__ qscale)
{
    if (blockIdx.x == 0 && threadIdx.x < DH) {
        float s = qs_scale[threadIdx.x];
        float sp = (s > 20.f) ? s : log1pf(expf(s));
        qscale[threadIdx.x] = 1.442695041f * sp * 0.125f * 1.442695041f;
    }
    int i = blockIdx.x * 256 + threadIdx.x;   // 512 blocks -> 131072 chunks
    const float* src; u16* dst; size_t off;
    if (i < 98304) { src = wi; dst = wib; off = (size_t)i * 8; }
    else           { src = wo; dst = wob; off = (size_t)(i - 98304) * 8; }
    float4 a = *(const float4*)(src + off);
    float4 b = *(const float4*)(src + off + 4);
    u16x8 r;
    r[0] = f2b(a.x); r[1] = f2b(a.y); r[2] = f2b(a.z); r[3] = f2b(a.w);
    r[4] = f2b(b.x); r[5] = f2b(b.y); r[6] = f2b(b.z); r[7] = f2b(b.w);
    *(u16x8*)(dst + off) = r;
}

// ---------------- bf16 MFMA GEMM: C = A(M,512) @ W(N,512)^T + bias --------
// (verified r28/r31 structure; grid dim3(M/128, N/128). Six structural
// variants tried — reg-staged, m97-graft, counted-vmcnt, A-prefetch,
// grid-swap, 256x128 tile — all neutral/worse; this is the plateau.)
template<int MODE>
__global__ __launch_bounds__(256) void gemm_bf16(
    const float* __restrict__ Af32, const u16* __restrict__ A16,
    const u16* __restrict__ W,
    const float* __restrict__ bias, const float* __restrict__ qscale,
    float* __restrict__ Dout, u16* __restrict__ Qb, u16* __restrict__ Kb,
    u16* __restrict__ Vtb)
{
    __shared__ u16 sA[2][4096];                // 2 x 8KB (512 slots x 16B)
    __shared__ u16 sB[2][4096];
    const int tid = threadIdx.x;
    const int m0 = blockIdx.x * 128;
    const int n0 = blockIdx.y * 128;
    const int wid = tid >> 6, lane = tid & 63;
    const int g = lane >> 4, c = lane & 15;
    const int wr = wid >> 1, wc = wid & 1;

    const int arow = tid >> 2;                 // 0..63 (covers arow, arow+64)
    const int swg = (arow & 3) ^ ((arow >> 2) & 3);
    const int ch = (tid & 3) ^ swg;            // inverse-swizzled chunk (DMA)
    const u16* Bsrc = W + (size_t)(n0 + arow) * 512 + ch * 8;
    const u16* A16src = A16 + (size_t)(m0 + arow) * 512 + ch * 8;
    // fp32 A: linear coalesced source; swizzle applied on the ds_write side
    const float* Afs = Af32 + (size_t)(m0 + arow) * 512 + (tid & 3) * 8;
    const int aslot0 = (arow * 4 + ((tid & 3) ^ swg)) * 8;        // u16 idx
    const int aslot1 = ((arow + 64) * 4 + ((tid & 3) ^ swg)) * 8;

    auto stageB = [&](int nbuf, int ks) {
        const int k0 = ks * 32;
        __builtin_amdgcn_global_load_lds(
            (const __attribute__((address_space(1))) unsigned int*)(Bsrc + k0),
            (__attribute__((address_space(3))) unsigned int*)&sB[nbuf][wid * 512], 16, 0, 0);
        __builtin_amdgcn_global_load_lds(
            (const __attribute__((address_space(1))) unsigned int*)(Bsrc + (size_t)64 * 512 + k0),
            (__attribute__((address_space(3))) unsigned int*)&sB[nbuf][2048 + wid * 512], 16, 0, 0);
    };
    auto stageA16 = [&](int nbuf, int ks) {
        const int k0 = ks * 32;
        __builtin_amdgcn_global_load_lds(
            (const __attribute__((address_space(1))) unsigned int*)(A16src + k0),
            (__attribute__((address_space(3))) unsigned int*)&sA[nbuf][wid * 512], 16, 0, 0);
        __builtin_amdgcn_global_load_lds(
            (const __attribute__((address_space(1))) unsigned int*)(A16src + (size_t)64 * 512 + k0),
            (__attribute__((address_space(3))) unsigned int*)&sA[nbuf][2048 + wid * 512], 16, 0, 0);
    };

    f32x4 acc[4][4];
    #pragma unroll
    for (int m = 0; m < 4; m++)
        #pragma unroll
        for (int n = 0; n < 4; n++) acc[m][n] = (f32x4){0.f, 0.f, 0.f, 0.f};

    const int swr = (c & 3) ^ ((c >> 2) & 3);
    const int chA = (g ^ swr) * 8;

    float4 a0, a1, a2, a3;                     // fp32 A regs (MODE 0)
    if (MODE == 0) {
        a0 = *(const float4*)(Afs);
        a1 = *(const float4*)(Afs + 4);
        a2 = *(const float4*)(Afs + (size_t)64 * 512);
        a3 = *(const float4*)(Afs + (size_t)64 * 512 + 4);
        stageB(0, 0);
    } else {
        stageA16(0, 0);
        stageB(0, 0);
    }

    #pragma unroll 1
    for (int ks = 0; ks < 16; ks++) {
        const int cur = ks & 1;
        if (MODE == 0) {
            // convert + write A(ks) into sA[cur] (auto vmcnt wait on a0..a3)
            uint4 w0, w1;
            w0.x = cvt_pk_bf16(a0.x, a0.y); w0.y = cvt_pk_bf16(a0.z, a0.w);
            w0.z = cvt_pk_bf16(a1.x, a1.y); w0.w = cvt_pk_bf16(a1.z, a1.w);
            w1.x = cvt_pk_bf16(a2.x, a2.y); w1.y = cvt_pk_bf16(a2.z, a2.w);
            w1.z = cvt_pk_bf16(a3.x, a3.y); w1.w = cvt_pk_bf16(a3.z, a3.w);
            *(uint4*)&sA[cur][aslot0] = w0;
            *(uint4*)&sA[cur][aslot1] = w1;
        }
        asm volatile("s_waitcnt vmcnt(0) lgkmcnt(0)" ::: "memory");
        __builtin_amdgcn_s_barrier();
        asm volatile("" ::: "memory");
        if (ks < 15) {
            if (MODE == 0) {
                const float* p = Afs + (ks + 1) * 32;
                a0 = *(const float4*)(p);
                a1 = *(const float4*)(p + 4);
                a2 = *(const float4*)(p + (size_t)64 * 512);
                a3 = *(const float4*)(p + (size_t)64 * 512 + 4);
            } else {
                stageA16(cur ^ 1, ks + 1);
            }
            stageB(cur ^ 1, ks + 1);           // after barrier: readers done
        }

        bf16x8 af[4], bfr[4];
        #pragma unroll
        for (int m = 0; m < 4; m++)
            af[m] = *(const bf16x8*)&sA[cur][(wr * 64 + m * 16 + c) * 32 + chA];
        #pragma unroll
        for (int n = 0; n < 4; n++)
            bfr[n] = *(const bf16x8*)&sB[cur][(wc * 64 + n * 16 + c) * 32 + chA];
        #pragma unroll
        for (int m = 0; m < 4; m++)
            #pragma unroll
            for (int n = 0; n < 4; n++)
                acc[m][n] = MFMA16(af[m], bfr[n], acc[m][n]);
    }

    #pragma unroll
    for (int m = 0; m < 4; m++) {
        int rbase = m0 + wr * 64 + m * 16 + 4 * g;
        #pragma unroll
        for (int n = 0; n < 4; n++) {
            int f = n0 + wc * 64 + n * 16 + c;
            f32x4 v = acc[m][n];
            float bv = bias[f];
            if (MODE == 1) {
                #pragma unroll
                for (int reg = 0; reg < 4; reg++)
                    Dout[(size_t)(rbase + reg) * E_ + f] = v[reg] + bv;
            } else {
                int part = f >> 9, w = f & 511, h = w >> 6, d = w & 63;
                int bb = rbase >> 10;
                int l0 = rbase & 1023;
                size_t bh = (size_t)(bb * H_ + h);
                if (part == 0) {
                    float qs = qscale[d];
                    #pragma unroll
                    for (int reg = 0; reg < 4; reg++)
                        Qb[(bh * L_ + l0 + reg) * DH + d] = f2b((v[reg] + bv) * qs);
                } else if (part == 1) {
                    #pragma unroll
                    for (int reg = 0; reg < 4; reg++)
                        Kb[(bh * L_ + l0 + reg) * DH + d] = f2b(v[reg] + bv);
                } else {
                    ushort4 pk;
                    pk.x = f2b(v[0] + bv); pk.y = f2b(v[1] + bv);
                    pk.z = f2b(v[2] + bv); pk.w = f2b(v[3] + bv);
                    *(ushort4*)(Vtb + (bh * DH + d) * L_ + l0) = pk;
                }
            }
        }
    }
}

// ---------------- MFMA flash attention, 8-wave blocks, role-split staging --
// (verified round-31: 512-thread blocks, 4 blocks/bh, wave-role-split K/V
// DMA, depth-3 counted vmcnt, no-shift softmax, denominator on MFMA, T12)
__global__ __launch_bounds__(512, 4) void attn_mfma(
    const u16* __restrict__ Q, const u16* __restrict__ K,
    const u16* __restrict__ Vt, const unsigned char* __restrict__ mask,
    u16* __restrict__ O)
{
    __shared__ u16 Kbuf[4][2048];              // 4 x 4KB (256 slots x 16B)
    __shared__ u16 Vbuf[4][2048];              // 4 x 4KB

    const int bid = blockIdx.x;                // 0..511
    const int w = (bid & 7) * 64 + (bid >> 3); // XCD-bijective swizzle
    const int bh = w >> 2;                     // 0..127
    const int blk = w & 3;                     // 0..3 within bh
    const int tid = threadIdx.x;
    const int wid = tid >> 6;                  // 0..7
    const int q0 = blk * 256 + wid * 32;       // wave's q base
    const int b = bh >> 3;
    const int h = bh & (H_ - 1);

    const int lane = tid & 63;
    const int c = lane & 31;                   // MFMA32 column
    const int hi = lane >> 5;

    const u16* Qp = Q + ((size_t)bh * L_ + q0) * DH;
    const u16* Kp = K + (size_t)bh * L_ * DH;
    const u16* Vp = Vt + (size_t)bh * DH * L_;
    const unsigned char* mp = mask + (size_t)b * L_;

    // role-split staging: wave quarter kvw covers slots [kvw*64, kvw*64+64)
    const int kvw = wid & 3;
    const bool isV = (wid >= 4);
    const int slot = kvw * 64 + lane;
    const int krow = slot >> 3, kch = (slot & 7) ^ (krow & 7);
    const int vrow = slot >> 2, vch = (slot & 3) ^ ((vrow & 3) ^ ((vrow >> 2) & 3));
    const u16* Kg = Kp + (size_t)krow * DH + kch * 8;   // + kt*DH per tile
    const u16* Vg = Vp + (size_t)vrow * L_ + vch * 8;   // + kt per tile

    auto stage = [&](int nbuf, int kt) {       // ONE DMA per wave
        if (!isV) {
            __builtin_amdgcn_global_load_lds(
                (const __attribute__((address_space(1))) unsigned int*)(Kg + (size_t)kt * DH),
                (__attribute__((address_space(3))) unsigned int*)&Kbuf[nbuf][kvw * 512],
                16, 0, 0);
        } else {
            __builtin_amdgcn_global_load_lds(
                (const __attribute__((address_space(1))) unsigned int*)(Vg + kt),
                (__attribute__((address_space(3))) unsigned int*)&Vbuf[nbuf][kvw * 512],
                16, 0, 0);
        }
    };

    // mask presence + Q fragments issued BEFORE the stages
    unsigned int mor = 0;
    {
        const unsigned int* mp32 = (const unsigned int*)mp;
        #pragma unroll
        for (int i = 0; i < 4; i++) mor |= mp32[lane + i * 64];
    }
    const bool anyMask = (__ballot(mor != 0) != 0ULL);

    bf16x8 qf[4];
    #pragma unroll
    for (int s2 = 0; s2 < 4; s2++)
        qf[s2] = *(const bf16x8*)(Qp + c * DH + s2 * 16 + hi * 8);

    stage(0, 0);                               // prefetch tiles 0,1,2
    stage(1, 32);
    stage(2, 64);

    f32x16 oacc0 = {}, oacc1 = {};
    f32x16 lacc = {};                          // denominator, row space

    // all-ones bf16 B-operand for the denominator matvec
    union { unsigned int u[4]; bf16x8 v; } onesu;
    onesu.u[0] = 0x3F803F80u; onesu.u[1] = 0x3F803F80u;
    onesu.u[2] = 0x3F803F80u; onesu.u[3] = 0x3F803F80u;
    const bf16x8 ones_b = onesu.v;

    // read-side swizzled LDS offsets (u16 indices)
    int kslot[4];
    #pragma unroll
    for (int s2 = 0; s2 < 4; s2++)
        kslot[s2] = (c * 8 + (((2 * s2 + hi)) ^ (c & 7))) * 8;
    const int swzv = (c & 3) ^ ((c >> 2) & 3);
    int vslot[2][2];
    #pragma unroll
    for (int dt = 0; dt < 2; dt++)
        #pragma unroll
        for (int s = 0; s < 2; s++)
            vslot[dt][s] = ((dt * 32 + c) * 4 + (((2 * s + hi)) ^ swzv)) * 8;

    #pragma unroll 1
    for (int t = 0; t < 32; ++t) {
        const int cur = t & 3;
        const int kt = t * 32;
        // counted wait: retire this wave's stage(t) (1 DMA per stage)
        if (t < 30)      { asm volatile("s_waitcnt vmcnt(2) lgkmcnt(0)" ::: "memory"); }
        else if (t == 30){ asm volatile("s_waitcnt vmcnt(1) lgkmcnt(0)" ::: "memory"); }
        else             { asm volatile("s_waitcnt vmcnt(0) lgkmcnt(0)" ::: "memory"); }
        __builtin_amdgcn_s_barrier();
        asm volatile("" ::: "memory");

        bf16x8 kf[4];
        #pragma unroll
        for (int s2 = 0; s2 < 4; s2++)
            kf[s2] = *(const bf16x8*)&Kbuf[cur][kslot[s2]];
        bf16x8 vf[2][2];
        #pragma unroll
        for (int dt = 0; dt < 2; dt++)
            #pragma unroll
            for (int s = 0; s < 2; s++)
                vf[dt][s] = *(const bf16x8*)&Vbuf[cur][vslot[dt][s]];

        if (t < 29) stage((t + 3) & 3, kt + 96);   // keep depth-3 in flight

        // S^T = K @ Q^T : lane holds S^T[key=(r&3)+8*(r>>2)+4*hi][q=c]
        f32x16 st = {};
        __builtin_amdgcn_s_setprio(1);
        #pragma unroll
        for (int s2 = 0; s2 < 4; s2++)
            st = MFMA32(kf[s2], qf[s2], st);
        __builtin_amdgcn_s_setprio(0);

        if (anyMask) {
            #pragma unroll
            for (int r = 0; r < 16; r++) {
                int key = kt + (r & 3) + 8 * (r >> 2) + 4 * hi;
                if (mp[key]) st[r] = -1e9f;
            }
        }

        // no-shift softmax: p = 2^st (shift unnecessary; ratio cancels it)
        float p[16];
        #pragma unroll
        for (int r = 0; r < 16; r++) p[r] = exp2_hw(st[r]);

        // in-register P redistribution (T12): cvt_pk + permlane32_swap
        unsigned int x0 = cvt_pk_bf16(p[0],  p[1]);
        unsigned int x1 = cvt_pk_bf16(p[2],  p[3]);
        unsigned int y0 = cvt_pk_bf16(p[4],  p[5]);
        unsigned int y1 = cvt_pk_bf16(p[6],  p[7]);
        unsigned int x2 = cvt_pk_bf16(p[8],  p[9]);
        unsigned int x3 = cvt_pk_bf16(p[10], p[11]);
        unsigned int y2 = cvt_pk_bf16(p[12], p[13]);
        unsigned int y3 = cvt_pk_bf16(p[14], p[15]);
        asm volatile("v_permlane32_swap_b32 %0, %1" : "+v"(x0), "+v"(y0));
        asm volatile("v_permlane32_swap_b32 %0, %1" : "+v"(x1), "+v"(y1));
        asm volatile("v_permlane32_swap_b32 %0, %1" : "+v"(x2), "+v"(y2));
        asm volatile("v_permlane32_swap_b32 %0, %1" : "+v"(x3), "+v"(y3));
        union { unsigned int u[4]; bf16x8 v; } pk0u, pk1u;
        pk0u.u[0] = x0; pk0u.u[1] = x1; pk0u.u[2] = y0; pk0u.u[3] = y1;
        pk1u.u[0] = x2; pk1u.u[1] = x3; pk1u.u[2] = y2; pk1u.u[3] = y3;
        bf16x8 pa0 = pk0u.v;                   // A[row=q=c][key=hi*8+j]
        bf16x8 pa1 = pk1u.v;                   // A[row=q=c][key=16+hi*8+j]

        __builtin_amdgcn_s_setprio(1);
        oacc0 = MFMA32(pa0, vf[0][0], oacc0);
        oacc0 = MFMA32(pa1, vf[0][1], oacc0);
        oacc1 = MFMA32(pa0, vf[1][0], oacc1);
        oacc1 = MFMA32(pa1, vf[1][1], oacc1);
        // denominator matvec: lacc[r] += sum_k P[q=(r&3)+8(r>>2)+4hi][k]
        lacc = MFMA32(pa0, ones_b, lacc);
        lacc = MFMA32(pa1, ones_b, lacc);
        __builtin_amdgcn_s_setprio(0);
        // oacc: lane holds O[q=(r&3)+8*(r>>2)+4*hi][d = dt*32 + c]
    }

    #pragma unroll
    for (int r = 0; r < 16; r++) {
        int row = (r & 3) + 8 * (r >> 2) + 4 * hi;
        float inv = 1.f / lacc[r];             // row space, no shfl needed
        size_t base = ((size_t)(b * L_ + q0 + row)) * E_ + h * DH + c;
        O[base] = f2b(oacc0[r] * inv);
        O[base + 32] = f2b(oacc1[r] * inv);
    }
}

// ---------------- host launch ----------------
extern "C" void kernel_launch(void* const* d_in, const int* in_sizes, int n_in,
                              void* d_out, int out_size, void* d_ws, size_t ws_size,
                              hipStream_t stream) {
    const float* x     = (const float*)d_in[0];
    const float* w_in  = (const float*)d_in[1];
    const float* b_in  = (const float*)d_in[2];
    const float* w_out = (const float*)d_in[3];
    const float* b_out = (const float*)d_in[4];
    const float* qs    = (const float*)d_in[5];
    const unsigned char* mask = (const unsigned char*)d_in[6];
    float* out = (float*)d_out;

    char* base = (char*)d_ws;
    const size_t NELEM = (size_t)B_ * L_ * E_;   // 8388608
    float* qscale = (float*)base;                // 256 B
    u16* wib = (u16*)(base + 256);               // 786432
    u16* wob = wib + 786432;                     // 262144
    u16* Qb  = wob + 262144;
    u16* Kb  = Qb + NELEM;
    u16* Vtb = Kb + NELEM;
    u16* Ob  = Vtb + NELEM;

    cvt_bf16<<<512, 256, 0, stream>>>(w_in, w_out, qs, wib, wob, qscale);
    gemm_bf16<0><<<dim3(128, 12), 256, 0, stream>>>(
        x, nullptr, wib, b_in, qscale, nullptr, Qb, Kb, Vtb);
    attn_mfma<<<dim3(512), 512, 0, stream>>>(Qb, Kb, Vtb, mask, Ob);
    gemm_bf16<1><<<dim3(128, 4), 256, 0, stream>>>(
        nullptr, Ob, wob, b_out, nullptr, out, nullptr, nullptr, nullptr);
}